// Round 1
// baseline (288.600 us; speedup 1.0000x reference)
//
#include <hip/hip_runtime.h>

#define LQ 768
#define DIN 256
#define DB 128
#define NH 8
#define DH 32

// ---------------------------------------------------------------------------
// Kernel A: LN(x) + Q/K/V/gate projections. One block per row (768 x 256).
// ---------------------------------------------------------------------------
__global__ __launch_bounds__(256) void proj_kernel(
    const float* __restrict__ x, const float* __restrict__ lnw, const float* __restrict__ lnb,
    const float* __restrict__ Wq, const float* __restrict__ Wk, const float* __restrict__ Wv,
    const float* __restrict__ Wg, const float* __restrict__ bg,
    float* __restrict__ qb, float* __restrict__ kb, float* __restrict__ vb, float* __restrict__ gb)
{
    const int row = blockIdx.x, tid = threadIdx.x;
    __shared__ float xn[DIN];
    __shared__ float red[8];

    float xv = x[row * DIN + tid];
    float s = xv, ss = xv * xv;
    #pragma unroll
    for (int m = 32; m >= 1; m >>= 1) { s += __shfl_xor(s, m); ss += __shfl_xor(ss, m); }
    if ((tid & 63) == 0) { int w = tid >> 6; red[w] = s; red[4 + w] = ss; }
    __syncthreads();
    s  = red[0] + red[1] + red[2] + red[3];
    ss = red[4] + red[5] + red[6] + red[7];
    float mu  = s * (1.0f / DIN);
    float inv = rsqrtf(ss * (1.0f / DIN) - mu * mu + 1e-5f);
    xn[tid] = (xv - mu) * inv * lnw[tid] + lnb[tid];
    __syncthreads();

    float aq = 0.f, ak = 0.f, av = 0.f, ag = 0.f;
    for (int i = 0; i < DIN; i++) {
        float xi = xn[i];
        aq = fmaf(xi, Wq[i * DIN + tid], aq);
        ak = fmaf(xi, Wk[i * DIN + tid], ak);
        av = fmaf(xi, Wv[i * DIN + tid], av);
        ag = fmaf(xi, Wg[i * DIN + tid], ag);
    }
    qb[row * DIN + tid] = aq;
    kb[row * DIN + tid] = ak * 0.17677669529663687f;  // 1/sqrt(DH)
    vb[row * DIN + tid] = av;
    gb[row * DIN + tid] = 1.0f / (1.0f + __expf(-(ag + bg[tid])));
}

// ---------------------------------------------------------------------------
// Kernel B: per query row — stream bias row once (LN + @Wb fused), add q.k,
// softmax over keys, PV, gate, output projection. One block per row.
// ---------------------------------------------------------------------------
__global__ __launch_bounds__(256) void attn_kernel(
    const float* __restrict__ bias, const float* __restrict__ lbw, const float* __restrict__ lbb,
    const float* __restrict__ Wb, const float* __restrict__ qb, const float* __restrict__ kbuf,
    const float* __restrict__ vbuf, const float* __restrict__ gb,
    const float* __restrict__ Wo, const float* __restrict__ bo, float* __restrict__ out)
{
    const int qrow = blockIdx.x, tid = threadIdx.x;

    __shared__ float s_lds[LQ][9];      // logits, padded to 9 -> conflict-free
    __shared__ float q_lds[DIN];
    __shared__ float w_lds[DB], b_lds[DB];
    __shared__ float wb_sw[DB * NH];    // XOR-swizzled Wb
    __shared__ float inv_den[NH];
    __shared__ float ao[DIN];

    q_lds[tid] = qb[qrow * DIN + tid];
    if (tid < DB) { w_lds[tid] = lbw[tid]; b_lds[tid] = lbb[tid]; }
    // swizzle: bank index gets seg (=d>>5) XORed into bits 3..4 so the 4 segs
    // of one (i,h) read land in 4 distinct banks instead of one.
    for (int j = tid; j < DB * NH; j += 256) wb_sw[j ^ ((j >> 8) << 3)] = Wb[j];
    __syncthreads();

    // ---- Phase 1a: bias-row LN + @Wb. 4 lanes per key, 32 dims each. ----
    const int kk0 = tid >> 2;       // key within 64-key chunk
    const int seg = tid & 3;        // which 32-dim segment
    const int swz = seg << 3;
    for (int cb = 0; cb < LQ; cb += 64) {
        const int k = cb + kk0;
        const float* bp = bias + ((size_t)qrow * LQ + k) * DB + seg * 32;
        float v[32];
        #pragma unroll
        for (int i = 0; i < 32; i += 4) {
            float4 t = *reinterpret_cast<const float4*>(bp + i);
            v[i] = t.x; v[i + 1] = t.y; v[i + 2] = t.z; v[i + 3] = t.w;
        }
        float s = 0.f, ss = 0.f;
        #pragma unroll
        for (int i = 0; i < 32; i++) { s += v[i]; ss = fmaf(v[i], v[i], ss); }
        s += __shfl_xor(s, 1); ss += __shfl_xor(ss, 1);
        s += __shfl_xor(s, 2); ss += __shfl_xor(ss, 2);
        float mu  = s * (1.0f / DB);
        float inv = rsqrtf(ss * (1.0f / DB) - mu * mu + 1e-5f);
        float acc[NH] = {0, 0, 0, 0, 0, 0, 0, 0};
        #pragma unroll
        for (int i = 0; i < 32; i++) {
            const int d = seg * 32 + i;
            float bn = (v[i] - mu) * inv * w_lds[d] + b_lds[d];
            #pragma unroll
            for (int h = 0; h < NH; h++)
                acc[h] = fmaf(bn, wb_sw[(d * NH + h) ^ swz], acc[h]);
        }
        #pragma unroll
        for (int h = 0; h < NH; h++) { acc[h] += __shfl_xor(acc[h], 1); acc[h] += __shfl_xor(acc[h], 2); }
        if (seg == 0) {
            #pragma unroll
            for (int h = 0; h < NH; h++) s_lds[k][h] = acc[h];
        }
    }
    __syncthreads();

    // ---- Phase 1b: += q.k (32 lanes per head, broadcast q reads) ----
    {
        const int h = tid >> 5, l = tid & 31;
        const float* qp = q_lds + h * DH;
        for (int k = l; k < LQ; k += 32) {
            const float* kp = kbuf + k * DIN + h * DH;
            float acc = 0.f;
            #pragma unroll
            for (int d = 0; d < DH; d++) acc = fmaf(qp[d], kp[d], acc);
            s_lds[k][h] += acc;
        }
    }
    __syncthreads();

    // ---- Phase 2: softmax over keys per head ----
    {
        const int h = tid >> 5, l = tid & 31;
        float m = -1e30f;
        for (int k = l; k < LQ; k += 32) m = fmaxf(m, s_lds[k][h]);
        #pragma unroll
        for (int msk = 16; msk >= 1; msk >>= 1) m = fmaxf(m, __shfl_xor(m, msk));
        float sum = 0.f;
        for (int k = l; k < LQ; k += 32) {
            float e = __expf(s_lds[k][h] - m);
            s_lds[k][h] = e;
            sum += e;
        }
        #pragma unroll
        for (int msk = 16; msk >= 1; msk >>= 1) sum += __shfl_xor(sum, msk);
        if (l == 0) inv_den[h] = 1.0f / sum;
    }
    __syncthreads();

    // ---- Phase 3: PV + gate ----
    {
        const int h = tid >> 5, d = tid & 31;
        float acc = 0.f;
        for (int k = 0; k < LQ; k++)
            acc = fmaf(s_lds[k][h], vbuf[k * DIN + h * DH + d], acc);
        ao[tid] = acc * inv_den[h] * gb[qrow * DIN + tid];
    }
    __syncthreads();

    // ---- Phase 4: output projection ----
    {
        float acc = bo[tid];
        for (int i = 0; i < DIN; i++) acc = fmaf(ao[i], Wo[i * DIN + tid], acc);
        out[qrow * DIN + tid] = acc;
    }
}

extern "C" void kernel_launch(void* const* d_in, const int* in_sizes, int n_in,
                              void* d_out, int out_size, void* d_ws, size_t ws_size,
                              hipStream_t stream) {
    const float* x    = (const float*)d_in[0];
    const float* bias = (const float*)d_in[1];
    const float* lnw  = (const float*)d_in[2];
    const float* lnb  = (const float*)d_in[3];
    const float* lbw  = (const float*)d_in[4];
    const float* lbb  = (const float*)d_in[5];
    const float* Wq   = (const float*)d_in[6];
    const float* Wk   = (const float*)d_in[7];
    const float* Wv   = (const float*)d_in[8];
    const float* Wb   = (const float*)d_in[9];
    const float* Wg   = (const float*)d_in[10];
    const float* bg   = (const float*)d_in[11];
    const float* Wo   = (const float*)d_in[12];
    const float* bo   = (const float*)d_in[13];

    float* ws = (float*)d_ws;
    float* qb = ws;
    float* kb = ws + 1 * LQ * DIN;
    float* vb = ws + 2 * LQ * DIN;
    float* gb = ws + 3 * LQ * DIN;

    proj_kernel<<<LQ, 256, 0, stream>>>(x, lnw, lnb, Wq, Wk, Wv, Wg, bg, qb, kb, vb, gb);
    attn_kernel<<<LQ, 256, 0, stream>>>(bias, lbw, lbb, Wb, qb, kb, vb, gb, Wo, bo, (float*)d_out);
}

// Round 3
// 260.661 us; speedup vs baseline: 1.1072x; 1.1072x over previous
//
#include <hip/hip_runtime.h>

#define LQ 768
#define DIN 256
#define DB 128
#define NH 8
#define DH 32

// ws layout (float offsets). Total ~22.0 MB.
#define OFF_QB 0
#define OFF_KB (LQ*DIN)
#define OFF_VB (2*LQ*DIN)
#define OFF_GB (3*LQ*DIN)
#define OFF_W2 (4*LQ*DIN)
#define OFF_SC (OFF_W2 + DB*NH)
#define OFF_LG (OFF_SC + 16)

// ---------------------------------------------------------------------------
// Setup: W2[d][h] = lbw[d]*Wb[d][h]; S[h] = sum_d W2; C[h] = sum_d lbb[d]*Wb.
// Folds the bias layernorm into the Wb projection.
// ---------------------------------------------------------------------------
__global__ __launch_bounds__(128) void setup_kernel(
    const float* __restrict__ lbw, const float* __restrict__ lbb,
    const float* __restrict__ Wb, float* __restrict__ W2, float* __restrict__ SC)
{
    const int d = threadIdx.x;          // 0..127
    const int lane = d & 63, wv = d >> 6;
    float w = lbw[d], b = lbb[d];
    float pS[NH], pC[NH];
    #pragma unroll
    for (int h = 0; h < NH; h++) {
        float wb = Wb[d*NH + h];
        float w2 = w * wb;
        W2[d*NH + h] = w2;
        pS[h] = w2;
        pC[h] = b * wb;
    }
    #pragma unroll
    for (int m = 1; m <= 32; m <<= 1) {
        #pragma unroll
        for (int h = 0; h < NH; h++) { pS[h] += __shfl_xor(pS[h], m); pC[h] += __shfl_xor(pC[h], m); }
    }
    __shared__ float red[2][16];
    if (lane == 0) {
        #pragma unroll
        for (int h = 0; h < NH; h++) { red[wv][h] = pS[h]; red[wv][NH+h] = pC[h]; }
    }
    __syncthreads();
    if (d < 16) SC[d] = red[0][d] + red[1][d];
}

// ---------------------------------------------------------------------------
// Proj: LN(x) + Q/K/V/gate. 4 rows per block; weight reads shared across rows.
// ---------------------------------------------------------------------------
__global__ __launch_bounds__(256) void proj_kernel(
    const float* __restrict__ x, const float* __restrict__ lnw, const float* __restrict__ lnb,
    const float* __restrict__ Wq, const float* __restrict__ Wk, const float* __restrict__ Wv,
    const float* __restrict__ Wg, const float* __restrict__ bg,
    float* __restrict__ qb, float* __restrict__ kb, float* __restrict__ vb, float* __restrict__ gb)
{
    const int tid = threadIdx.x;
    const int lane = tid & 63, rr = tid >> 6;
    const int row = blockIdx.x * 4 + rr;
    __shared__ float xn[4][DIN];

    float4 xv = ((const float4*)x)[row * (DIN/4) + lane];
    float s  = xv.x + xv.y + xv.z + xv.w;
    float ss = xv.x*xv.x + xv.y*xv.y + xv.z*xv.z + xv.w*xv.w;
    #pragma unroll
    for (int m = 1; m <= 32; m <<= 1) { s += __shfl_xor(s, m); ss += __shfl_xor(ss, m); }
    float mu  = s * (1.0f/DIN);
    float inv = rsqrtf(ss * (1.0f/DIN) - mu*mu + 1e-5f);
    float4 wv4 = ((const float4*)lnw)[lane];
    float4 bv4 = ((const float4*)lnb)[lane];
    float4 r4;
    r4.x = (xv.x - mu)*inv*wv4.x + bv4.x;
    r4.y = (xv.y - mu)*inv*wv4.y + bv4.y;
    r4.z = (xv.z - mu)*inv*wv4.z + bv4.z;
    r4.w = (xv.w - mu)*inv*wv4.w + bv4.w;
    *((float4*)&xn[rr][lane*4]) = r4;
    __syncthreads();

    const int col = tid;
    float aq[4] = {0,0,0,0}, ak[4] = {0,0,0,0}, av[4] = {0,0,0,0}, ag[4] = {0,0,0,0};
    for (int i4 = 0; i4 < DIN/4; i4++) {
        float4 x0 = *((const float4*)&xn[0][i4*4]);
        float4 x1 = *((const float4*)&xn[1][i4*4]);
        float4 x2 = *((const float4*)&xn[2][i4*4]);
        float4 x3 = *((const float4*)&xn[3][i4*4]);
        const float* p0 = (const float*)&x0;
        const float* p1 = (const float*)&x1;
        const float* p2 = (const float*)&x2;
        const float* p3 = (const float*)&x3;
        #pragma unroll
        for (int e = 0; e < 4; e++) {
            const int i = i4*4 + e;
            float wq = Wq[i*DIN + col], wk = Wk[i*DIN + col];
            float wvv = Wv[i*DIN + col], wg = Wg[i*DIN + col];
            aq[0] = fmaf(p0[e], wq, aq[0]); aq[1] = fmaf(p1[e], wq, aq[1]);
            aq[2] = fmaf(p2[e], wq, aq[2]); aq[3] = fmaf(p3[e], wq, aq[3]);
            ak[0] = fmaf(p0[e], wk, ak[0]); ak[1] = fmaf(p1[e], wk, ak[1]);
            ak[2] = fmaf(p2[e], wk, ak[2]); ak[3] = fmaf(p3[e], wk, ak[3]);
            av[0] = fmaf(p0[e], wvv, av[0]); av[1] = fmaf(p1[e], wvv, av[1]);
            av[2] = fmaf(p2[e], wvv, av[2]); av[3] = fmaf(p3[e], wvv, av[3]);
            ag[0] = fmaf(p0[e], wg, ag[0]); ag[1] = fmaf(p1[e], wg, ag[1]);
            ag[2] = fmaf(p2[e], wg, ag[2]); ag[3] = fmaf(p3[e], wg, ag[3]);
        }
    }
    const float kscale = 0.17677669529663687f;  // 1/sqrt(DH)
    float bgv = bg[col];
    #pragma unroll
    for (int r = 0; r < 4; r++) {
        const int orow = blockIdx.x*4 + r;
        qb[orow*DIN + col] = aq[r];
        kb[orow*DIN + col] = ak[r] * kscale;
        vb[orow*DIN + col] = av[r];
        gb[orow*DIN + col] = 1.0f/(1.0f + __expf(-(ag[r] + bgv)));
    }
}

// ---------------------------------------------------------------------------
// Bias stream: folded LN + @Wb + fused PER-HEAD q.k -> final pre-softmax
// logits. Grid (12, 768); block 256: seg = tid&7 covers bias dims
// seg*16..+15 AND q/k dims seg*32..+31 (== head seg exactly, DH==32).
// ---------------------------------------------------------------------------
__global__ __launch_bounds__(256) void bias_kernel(
    const float* __restrict__ bias, const float* __restrict__ W2g, const float* __restrict__ SCg,
    const float* __restrict__ qbuf, const float* __restrict__ kbuf, float* __restrict__ logits)
{
    const int tid = threadIdx.x;
    const int q = blockIdx.y;
    const int cb = blockIdx.x * 64;

    __shared__ float w2s[DB*NH];   // XOR-swizzled: j ^ (((j>>7)&3)<<3)
    __shared__ float qs[DIN];      // XOR-swizzled: i ^ (((i>>5)&3)<<2)

    {
        int j = tid * 4;
        float4 t = ((const float4*)W2g)[tid];
        int sw = j ^ (((j >> 7) & 3) << 3);
        *((float4*)&w2s[sw]) = t;
        if (tid < 64) {
            int i = tid * 4;
            float4 qv = ((const float4*)(qbuf + q*DIN))[tid];
            int sq = i ^ (((i >> 5) & 3) << 2);
            *((float4*)&qs[sq]) = qv;
        }
    }
    float Sarr[NH], Carr[NH];
    #pragma unroll
    for (int h = 0; h < NH; h++) { Sarr[h] = SCg[h]; Carr[h] = SCg[NH + h]; }
    __syncthreads();

    const int seg  = tid & 7;
    const int slot = (tid >> 3) & 7;
    const int wv   = tid >> 6;
    const int lane = tid & 63;
    const int kA = cb + wv*16 + slot;
    const int kB = kA + 8;

    const float* bA = bias + ((size_t)q*LQ + kA)*DB + seg*16;
    const float* bB = bA + 8*DB;

    float sA = 0.f, ssA = 0.f, sB = 0.f, ssB = 0.f;
    float accA[NH] = {0,0,0,0,0,0,0,0};
    float accB[NH] = {0,0,0,0,0,0,0,0};
    const int wsw = (seg & 3) << 3;

    #pragma unroll
    for (int i4 = 0; i4 < 4; i4++) {
        float4 a  = *((const float4*)(bA + i4*4));
        float4 b4 = *((const float4*)(bB + i4*4));
        const float* ap = (const float*)&a;
        const float* bp = (const float*)&b4;
        #pragma unroll
        for (int e = 0; e < 4; e++) {
            float va = ap[e], vb_ = bp[e];
            sA += va; ssA = fmaf(va, va, ssA);
            sB += vb_; ssB = fmaf(vb_, vb_, ssB);
            const int d = seg*16 + i4*4 + e;
            const int l0 = (d*NH) ^ wsw;
            float4 w0 = *((const float4*)&w2s[l0]);
            float4 w1 = *((const float4*)&w2s[l0 + 4]);
            accA[0] = fmaf(va, w0.x, accA[0]); accA[1] = fmaf(va, w0.y, accA[1]);
            accA[2] = fmaf(va, w0.z, accA[2]); accA[3] = fmaf(va, w0.w, accA[3]);
            accA[4] = fmaf(va, w1.x, accA[4]); accA[5] = fmaf(va, w1.y, accA[5]);
            accA[6] = fmaf(va, w1.z, accA[6]); accA[7] = fmaf(va, w1.w, accA[7]);
            accB[0] = fmaf(vb_, w0.x, accB[0]); accB[1] = fmaf(vb_, w0.y, accB[1]);
            accB[2] = fmaf(vb_, w0.z, accB[2]); accB[3] = fmaf(vb_, w0.w, accB[3]);
            accB[4] = fmaf(vb_, w1.x, accB[4]); accB[5] = fmaf(vb_, w1.y, accB[5]);
            accB[6] = fmaf(vb_, w1.z, accB[6]); accB[7] = fmaf(vb_, w1.w, accB[7]);
        }
    }

    // per-head q.k: this thread's seg == head index; dims seg*32..+31 are the
    // COMPLETE head-seg dot (no cross-seg reduction needed).
    float qkA = 0.f, qkB = 0.f;
    {
        const float* kAp = kbuf + kA*DIN + seg*32;
        const float* kBp = kbuf + kB*DIN + seg*32;
        const int qsw_ = (seg & 3) << 2;
        #pragma unroll
        for (int j4 = 0; j4 < 8; j4++) {
            const int qi = (seg*32 + j4*4) ^ qsw_;
            float4 qv  = *((const float4*)&qs[qi]);
            float4 ka  = *((const float4*)(kAp + j4*4));
            float4 kb4 = *((const float4*)(kBp + j4*4));
            qkA = fmaf(qv.x, ka.x, qkA); qkA = fmaf(qv.y, ka.y, qkA);
            qkA = fmaf(qv.z, ka.z, qkA); qkA = fmaf(qv.w, ka.w, qkA);
            qkB = fmaf(qv.x, kb4.x, qkB); qkB = fmaf(qv.y, kb4.y, qkB);
            qkB = fmaf(qv.z, kb4.z, qkB); qkB = fmaf(qv.w, kb4.w, qkB);
        }
    }

    // reduce bias stats/proj over the 8 segs (lane bits 0..2)
    #pragma unroll
    for (int m = 1; m <= 4; m <<= 1) {
        sA += __shfl_xor(sA, m);  ssA += __shfl_xor(ssA, m);
        sB += __shfl_xor(sB, m);  ssB += __shfl_xor(ssB, m);
        #pragma unroll
        for (int h = 0; h < NH; h++) {
            accA[h] += __shfl_xor(accA[h], m);
            accB[h] += __shfl_xor(accB[h], m);
        }
    }

    // redistribute per-head qk: lane with seg==h holds head h's dot.
    // All lanes active here (shuffle before the divergent store).
    float qkhA[NH], qkhB[NH];
    const int base = lane & 56;
    #pragma unroll
    for (int h = 0; h < NH; h++) {
        qkhA[h] = __shfl(qkA, base | h);
        qkhB[h] = __shfl(qkB, base | h);
    }

    if (seg == 0) {
        {
            float mu  = sA * (1.0f/DB);
            float inv = rsqrtf(ssA * (1.0f/DB) - mu*mu + 1e-5f);
            float lo[NH];
            #pragma unroll
            for (int h = 0; h < NH; h++)
                lo[h] = fmaf(inv, accA[h] - mu*Sarr[h], Carr[h]) + qkhA[h];
            float4* dst = (float4*)(logits + ((size_t)q*LQ + kA)*NH);
            dst[0] = make_float4(lo[0], lo[1], lo[2], lo[3]);
            dst[1] = make_float4(lo[4], lo[5], lo[6], lo[7]);
        }
        {
            float mu  = sB * (1.0f/DB);
            float inv = rsqrtf(ssB * (1.0f/DB) - mu*mu + 1e-5f);
            float lo[NH];
            #pragma unroll
            for (int h = 0; h < NH; h++)
                lo[h] = fmaf(inv, accB[h] - mu*Sarr[h], Carr[h]) + qkhB[h];
            float4* dst = (float4*)(logits + ((size_t)q*LQ + kB)*NH);
            dst[0] = make_float4(lo[0], lo[1], lo[2], lo[3]);
            dst[1] = make_float4(lo[4], lo[5], lo[6], lo[7]);
        }
    }
}

// ---------------------------------------------------------------------------
// Attn finish: softmax + PV + gate + Wo. 2 q-rows per block (V/Wo shared).
// ---------------------------------------------------------------------------
__global__ __launch_bounds__(256) void attn_kernel(
    const float* __restrict__ logits, const float* __restrict__ vbuf, const float* __restrict__ gb,
    const float* __restrict__ Wo, const float* __restrict__ bo, float* __restrict__ out)
{
    const int tid = threadIdx.x;
    const int q0 = blockIdx.x * 2;
    __shared__ float s2[2][LQ][9];      // pad 9 -> conflict-free strided access
    __shared__ float ao[2][DIN];
    __shared__ float isum[2][NH];

    for (int r = 0; r < 2; r++) {
        const float4* rp = (const float4*)(logits + (size_t)(q0 + r)*LQ*NH);
        for (int jj = tid; jj < LQ*NH/4; jj += 256) {
            float4 t = rp[jj];
            const int k = jj >> 1, h0 = (jj & 1) << 2;
            s2[r][k][h0+0] = t.x; s2[r][k][h0+1] = t.y;
            s2[r][k][h0+2] = t.z; s2[r][k][h0+3] = t.w;
        }
    }
    __syncthreads();

    {
        const int r = tid >> 7, h = (tid >> 4) & 7, l = tid & 15;
        float m = -1e30f;
        for (int k = l; k < LQ; k += 16) m = fmaxf(m, s2[r][k][h]);
        #pragma unroll
        for (int mm = 1; mm <= 8; mm <<= 1) m = fmaxf(m, __shfl_xor(m, mm));
        float sum = 0.f;
        for (int k = l; k < LQ; k += 16) {
            float e = __expf(s2[r][k][h] - m);
            s2[r][k][h] = e;
            sum += e;
        }
        #pragma unroll
        for (int mm = 1; mm <= 8; mm <<= 1) sum += __shfl_xor(sum, mm);
        if (l == 0) isum[r][h] = 1.0f / sum;
    }
    __syncthreads();

    {
        const int h = tid >> 5, d = tid & 31;
        const float* vp = vbuf + h*DH + d;
        float a00 = 0.f, a01 = 0.f, a10 = 0.f, a11 = 0.f;
        for (int k = 0; k < LQ; k += 2) {
            float v0 = vp[(size_t)k*DIN];
            float v1 = vp[(size_t)(k+1)*DIN];
            a00 = fmaf(s2[0][k][h],   v0, a00);
            a10 = fmaf(s2[1][k][h],   v0, a10);
            a01 = fmaf(s2[0][k+1][h], v1, a01);
            a11 = fmaf(s2[1][k+1][h], v1, a11);
        }
        ao[0][tid] = (a00 + a01) * isum[0][h] * gb[(q0+0)*DIN + tid];
        ao[1][tid] = (a10 + a11) * isum[1][h] * gb[(q0+1)*DIN + tid];
    }
    __syncthreads();

    {
        const int col = tid;
        float o0 = bo[col], o1 = o0;
        for (int i = 0; i < DIN; i++) {
            float w = Wo[i*DIN + col];
            o0 = fmaf(ao[0][i], w, o0);
            o1 = fmaf(ao[1][i], w, o1);
        }
        out[(q0+0)*DIN + col] = o0;
        out[(q0+1)*DIN + col] = o1;
    }
}

extern "C" void kernel_launch(void* const* d_in, const int* in_sizes, int n_in,
                              void* d_out, int out_size, void* d_ws, size_t ws_size,
                              hipStream_t stream) {
    const float* x    = (const float*)d_in[0];
    const float* bias = (const float*)d_in[1];
    const float* lnw  = (const float*)d_in[2];
    const float* lnb  = (const float*)d_in[3];
    const float* lbw  = (const float*)d_in[4];
    const float* lbb  = (const float*)d_in[5];
    const float* Wq   = (const float*)d_in[6];
    const float* Wk   = (const float*)d_in[7];
    const float* Wv   = (const float*)d_in[8];
    const float* Wb   = (const float*)d_in[9];
    const float* Wg   = (const float*)d_in[10];
    const float* bg   = (const float*)d_in[11];
    const float* Wo   = (const float*)d_in[12];
    const float* bo   = (const float*)d_in[13];

    float* ws = (float*)d_ws;
    float* qb = ws + OFF_QB;
    float* kb = ws + OFF_KB;
    float* vb = ws + OFF_VB;
    float* gb = ws + OFF_GB;
    float* W2 = ws + OFF_W2;
    float* SC = ws + OFF_SC;
    float* lg = ws + OFF_LG;

    setup_kernel<<<1, 128, 0, stream>>>(lbw, lbb, Wb, W2, SC);
    proj_kernel<<<LQ/4, 256, 0, stream>>>(x, lnw, lnb, Wq, Wk, Wv, Wg, bg, qb, kb, vb, gb);
    bias_kernel<<<dim3(12, LQ), 256, 0, stream>>>(bias, W2, SC, qb, kb, lg);
    attn_kernel<<<LQ/2, 256, 0, stream>>>(lg, vb, gb, Wo, bo, (float*)d_out);
}

// Round 4
// 215.658 us; speedup vs baseline: 1.3382x; 1.2087x over previous
//
#include <hip/hip_runtime.h>

#define LQ 768
#define DIN 256
#define DB 128
#define NH 8
#define DH 32

// ws float offsets
#define OFF_QB 0
#define OFF_KT (LQ*DIN)          // kT[DIN][LQ]  (transposed, pre-scaled K)
#define OFF_VB (2*LQ*DIN)
#define OFF_GB (3*LQ*DIN)
#define OFF_W2 (4*LQ*DIN)
#define OFF_SC (OFF_W2 + DB*NH)
#define OFF_LG (OFF_SC + 16)

// ---------------------------------------------------------------------------
// Setup: W2[d][h] = lbw[d]*Wb[d][h]; S[h] = sum_d W2; C[h] = sum_d lbb[d]*Wb.
// ---------------------------------------------------------------------------
__global__ __launch_bounds__(128) void setup_kernel(
    const float* __restrict__ lbw, const float* __restrict__ lbb,
    const float* __restrict__ Wb, float* __restrict__ W2, float* __restrict__ SC)
{
    const int d = threadIdx.x;          // 0..127
    const int lane = d & 63, wv = d >> 6;
    float w = lbw[d], b = lbb[d];
    float pS[NH], pC[NH];
    #pragma unroll
    for (int h = 0; h < NH; h++) {
        float wb = Wb[d*NH + h];
        float w2 = w * wb;
        W2[d*NH + h] = w2;
        pS[h] = w2;
        pC[h] = b * wb;
    }
    #pragma unroll
    for (int m = 1; m <= 32; m <<= 1) {
        #pragma unroll
        for (int h = 0; h < NH; h++) { pS[h] += __shfl_xor(pS[h], m); pC[h] += __shfl_xor(pC[h], m); }
    }
    __shared__ float red[2][16];
    if (lane == 0) {
        #pragma unroll
        for (int h = 0; h < NH; h++) { red[wv][h] = pS[h]; red[wv][NH+h] = pC[h]; }
    }
    __syncthreads();
    if (d < 16) SC[d] = red[0][d] + red[1][d];
}

// ---------------------------------------------------------------------------
// Proj: LN(x) + Q/K/V/gate. 4 rows/block. K written TRANSPOSED (kT[dim][key])
// and pre-scaled so attn can read kT rows contiguously.
// ---------------------------------------------------------------------------
__global__ __launch_bounds__(256) void proj_kernel(
    const float* __restrict__ x, const float* __restrict__ lnw, const float* __restrict__ lnb,
    const float* __restrict__ Wq, const float* __restrict__ Wk, const float* __restrict__ Wv,
    const float* __restrict__ Wg, const float* __restrict__ bg,
    float* __restrict__ qb, float* __restrict__ kT, float* __restrict__ vb, float* __restrict__ gb)
{
    const int tid = threadIdx.x;
    const int lane = tid & 63, rr = tid >> 6;
    const int row = blockIdx.x * 4 + rr;
    __shared__ float xn[4][DIN];

    float4 xv = ((const float4*)x)[row * (DIN/4) + lane];
    float s  = xv.x + xv.y + xv.z + xv.w;
    float ss = xv.x*xv.x + xv.y*xv.y + xv.z*xv.z + xv.w*xv.w;
    #pragma unroll
    for (int m = 1; m <= 32; m <<= 1) { s += __shfl_xor(s, m); ss += __shfl_xor(ss, m); }
    float mu  = s * (1.0f/DIN);
    float inv = rsqrtf(ss * (1.0f/DIN) - mu*mu + 1e-5f);
    float4 wv4 = ((const float4*)lnw)[lane];
    float4 bv4 = ((const float4*)lnb)[lane];
    float4 r4;
    r4.x = (xv.x - mu)*inv*wv4.x + bv4.x;
    r4.y = (xv.y - mu)*inv*wv4.y + bv4.y;
    r4.z = (xv.z - mu)*inv*wv4.z + bv4.z;
    r4.w = (xv.w - mu)*inv*wv4.w + bv4.w;
    *((float4*)&xn[rr][lane*4]) = r4;
    __syncthreads();

    const int col = tid;
    float aq[4] = {0,0,0,0}, ak[4] = {0,0,0,0}, av[4] = {0,0,0,0}, ag[4] = {0,0,0,0};
    for (int i4 = 0; i4 < DIN/4; i4++) {
        float4 x0 = *((const float4*)&xn[0][i4*4]);
        float4 x1 = *((const float4*)&xn[1][i4*4]);
        float4 x2 = *((const float4*)&xn[2][i4*4]);
        float4 x3 = *((const float4*)&xn[3][i4*4]);
        const float* p0 = (const float*)&x0;
        const float* p1 = (const float*)&x1;
        const float* p2 = (const float*)&x2;
        const float* p3 = (const float*)&x3;
        #pragma unroll
        for (int e = 0; e < 4; e++) {
            const int i = i4*4 + e;
            float wq = Wq[i*DIN + col], wk = Wk[i*DIN + col];
            float wvv = Wv[i*DIN + col], wg = Wg[i*DIN + col];
            aq[0] = fmaf(p0[e], wq, aq[0]); aq[1] = fmaf(p1[e], wq, aq[1]);
            aq[2] = fmaf(p2[e], wq, aq[2]); aq[3] = fmaf(p3[e], wq, aq[3]);
            ak[0] = fmaf(p0[e], wk, ak[0]); ak[1] = fmaf(p1[e], wk, ak[1]);
            ak[2] = fmaf(p2[e], wk, ak[2]); ak[3] = fmaf(p3[e], wk, ak[3]);
            av[0] = fmaf(p0[e], wvv, av[0]); av[1] = fmaf(p1[e], wvv, av[1]);
            av[2] = fmaf(p2[e], wvv, av[2]); av[3] = fmaf(p3[e], wvv, av[3]);
            ag[0] = fmaf(p0[e], wg, ag[0]); ag[1] = fmaf(p1[e], wg, ag[1]);
            ag[2] = fmaf(p2[e], wg, ag[2]); ag[3] = fmaf(p3[e], wg, ag[3]);
        }
    }
    const float kscale = 0.17677669529663687f;  // 1/sqrt(DH)
    float bgv = bg[col];
    #pragma unroll
    for (int r = 0; r < 4; r++) {
        const int orow = blockIdx.x*4 + r;
        qb[orow*DIN + col] = aq[r];
        vb[orow*DIN + col] = av[r];
        gb[orow*DIN + col] = 1.0f/(1.0f + __expf(-(ag[r] + bgv)));
    }
    // transposed, pre-scaled K: kT[col][key0..key0+3]
    *((float4*)&kT[col*LQ + blockIdx.x*4]) =
        make_float4(ak[0]*kscale, ak[1]*kscale, ak[2]*kscale, ak[3]*kscale);
}

// ---------------------------------------------------------------------------
// Bias stream: pure HBM stream. Grid (12, 768), block 256.
// Stage 64-key x 128-dim tile (32KB) with linear global float4 loads +
// XOR-swizzled ds_write (involution A ^= ((A>>9)&31)<<4). Each wave owns a
// uniform 32-dim quarter (q4) -> W2 rows become scalar (s_load) operands.
// Partials combined via small LDS array. No shuffles, no K, no Q.
// ---------------------------------------------------------------------------
__global__ __launch_bounds__(256) void bias_kernel(
    const float* __restrict__ bias, const float* __restrict__ W2g,
    const float* __restrict__ SCg, float* __restrict__ logits)
{
    __shared__ float tile[8192];        // 32KB
    __shared__ float part[4][10][65];   // [q4][slot][key] conflict-free
    const int tid = threadIdx.x;
    const int q = blockIdx.y;
    const int k0 = blockIdx.x * 64;

    const float* src = bias + ((size_t)q*LQ + k0)*DB;
    #pragma unroll
    for (int c = 0; c < 8; c++) {
        float4 t = *(const float4*)(src + c*1024 + tid*4);
        int A = c*4096 + tid*16;
        int sw = A ^ (((A>>9)&31)<<4);
        *(float4*)((char*)tile + sw) = t;
    }
    __syncthreads();

    const int key = tid & 63;
    const int q4  = __builtin_amdgcn_readfirstlane(tid >> 6);  // wave-uniform
    const int dbase = q4 * 32;

    float s = 0.f, ss = 0.f;
    float acc[NH] = {0,0,0,0,0,0,0,0};
    #pragma unroll
    for (int j4 = 0; j4 < 8; j4++) {
        int raw = key*512 + q4*128 + j4*16;
        int adr = raw ^ ((key & 31) << 4);
        float4 v = *(const float4*)((const char*)tile + adr);
        const float* wr = W2g + (dbase + j4*4)*NH;   // uniform -> s_load
        s += v.x; ss = fmaf(v.x, v.x, ss);
        s += v.y; ss = fmaf(v.y, v.y, ss);
        s += v.z; ss = fmaf(v.z, v.z, ss);
        s += v.w; ss = fmaf(v.w, v.w, ss);
        #pragma unroll
        for (int h = 0; h < NH; h++) acc[h] = fmaf(v.x, wr[h],      acc[h]);
        #pragma unroll
        for (int h = 0; h < NH; h++) acc[h] = fmaf(v.y, wr[NH+h],   acc[h]);
        #pragma unroll
        for (int h = 0; h < NH; h++) acc[h] = fmaf(v.z, wr[2*NH+h], acc[h]);
        #pragma unroll
        for (int h = 0; h < NH; h++) acc[h] = fmaf(v.w, wr[3*NH+h], acc[h]);
    }
    part[q4][0][key] = s;
    part[q4][1][key] = ss;
    #pragma unroll
    for (int h = 0; h < NH; h++) part[q4][2+h][key] = acc[h];
    __syncthreads();

    if (tid < 64) {
        float fs = 0.f, fss = 0.f, fa[NH] = {0,0,0,0,0,0,0,0};
        #pragma unroll
        for (int g = 0; g < 4; g++) {
            fs  += part[g][0][tid];
            fss += part[g][1][tid];
            #pragma unroll
            for (int h = 0; h < NH; h++) fa[h] += part[g][2+h][tid];
        }
        float mu  = fs * (1.0f/DB);
        float inv = rsqrtf(fss * (1.0f/DB) - mu*mu + 1e-5f);
        float lo[NH];
        #pragma unroll
        for (int h = 0; h < NH; h++)
            lo[h] = fmaf(inv, fa[h] - mu*SCg[h], SCg[NH+h]);
        float4* dst = (float4*)(logits + ((size_t)q*LQ + k0 + tid)*NH);
        dst[0] = make_float4(lo[0], lo[1], lo[2], lo[3]);
        dst[1] = make_float4(lo[4], lo[5], lo[6], lo[7]);
    }
}

// ---------------------------------------------------------------------------
// Attn: load bias-logits, add qk (computed here from kT), softmax, PV, gate,
// Wo. 2 q-rows per block, grid 384.
// ---------------------------------------------------------------------------
__global__ __launch_bounds__(256) void attn_kernel(
    const float* __restrict__ logits, const float* __restrict__ qbuf,
    const float* __restrict__ kT, const float* __restrict__ vbuf,
    const float* __restrict__ gb, const float* __restrict__ Wo,
    const float* __restrict__ bo, float* __restrict__ out)
{
    const int tid = threadIdx.x;
    const int q0 = blockIdx.x * 2;
    __shared__ float s2[2][LQ][9];
    __shared__ float ao[2][DIN];
    __shared__ float isum[2][NH];

    for (int r = 0; r < 2; r++) {
        const float4* rp = (const float4*)(logits + (size_t)(q0 + r)*LQ*NH);
        for (int jj = tid; jj < LQ*NH/4; jj += 256) {
            float4 t = rp[jj];
            const int k = jj >> 1, h0 = (jj & 1) << 2;
            s2[r][k][h0+0] = t.x; s2[r][k][h0+1] = t.y;
            s2[r][k][h0+2] = t.z; s2[r][k][h0+3] = t.w;
        }
    }
    __syncthreads();

    // qk: threads 0..191, 4 consecutive keys each, all 8 heads, both q rows.
    if (tid < 192) {
        float acc[2][4][NH];
        #pragma unroll
        for (int r = 0; r < 2; r++)
            #pragma unroll
            for (int e = 0; e < 4; e++)
                #pragma unroll
                for (int h = 0; h < NH; h++) acc[r][e][h] = 0.f;
        const float* q0p = qbuf + (size_t)q0*DIN;       // uniform -> s_load
        const float* q1p = q0p + DIN;
        #pragma unroll
        for (int h = 0; h < NH; h++) {
            #pragma unroll
            for (int dd = 0; dd < DH; dd++) {
                const int d = h*DH + dd;
                float4 kv = *(const float4*)(kT + (size_t)d*LQ + tid*4);
                float qa = q0p[d], qc = q1p[d];
                acc[0][0][h] = fmaf(qa, kv.x, acc[0][0][h]);
                acc[0][1][h] = fmaf(qa, kv.y, acc[0][1][h]);
                acc[0][2][h] = fmaf(qa, kv.z, acc[0][2][h]);
                acc[0][3][h] = fmaf(qa, kv.w, acc[0][3][h]);
                acc[1][0][h] = fmaf(qc, kv.x, acc[1][0][h]);
                acc[1][1][h] = fmaf(qc, kv.y, acc[1][1][h]);
                acc[1][2][h] = fmaf(qc, kv.z, acc[1][2][h]);
                acc[1][3][h] = fmaf(qc, kv.w, acc[1][3][h]);
            }
        }
        #pragma unroll
        for (int e = 0; e < 4; e++) {
            const int k = tid*4 + e;
            #pragma unroll
            for (int h = 0; h < NH; h++) {
                s2[0][k][h] += acc[0][e][h];
                s2[1][k][h] += acc[1][e][h];
            }
        }
    }
    __syncthreads();

    {
        const int r = tid >> 7, h = (tid >> 4) & 7, l = tid & 15;
        float m = -1e30f;
        for (int k = l; k < LQ; k += 16) m = fmaxf(m, s2[r][k][h]);
        #pragma unroll
        for (int mm = 1; mm <= 8; mm <<= 1) m = fmaxf(m, __shfl_xor(m, mm));
        float sum = 0.f;
        for (int k = l; k < LQ; k += 16) {
            float e = __expf(s2[r][k][h] - m);
            s2[r][k][h] = e;
            sum += e;
        }
        #pragma unroll
        for (int mm = 1; mm <= 8; mm <<= 1) sum += __shfl_xor(sum, mm);
        if (l == 0) isum[r][h] = 1.0f / sum;
    }
    __syncthreads();

    {
        const int h = tid >> 5, d = tid & 31;
        const float* vp = vbuf + h*DH + d;
        float a00 = 0.f, a01 = 0.f, a10 = 0.f, a11 = 0.f;
        for (int k = 0; k < LQ; k += 2) {
            float v0 = vp[(size_t)k*DIN];
            float v1 = vp[(size_t)(k+1)*DIN];
            a00 = fmaf(s2[0][k][h],   v0, a00);
            a10 = fmaf(s2[1][k][h],   v0, a10);
            a01 = fmaf(s2[0][k+1][h], v1, a01);
            a11 = fmaf(s2[1][k+1][h], v1, a11);
        }
        ao[0][tid] = (a00 + a01) * isum[0][h] * gb[(q0+0)*DIN + tid];
        ao[1][tid] = (a10 + a11) * isum[1][h] * gb[(q0+1)*DIN + tid];
    }
    __syncthreads();

    {
        const int col = tid;
        float o0 = bo[col], o1 = o0;
        for (int i = 0; i < DIN; i++) {
            float w = Wo[i*DIN + col];
            o0 = fmaf(ao[0][i], w, o0);
            o1 = fmaf(ao[1][i], w, o1);
        }
        out[(q0+0)*DIN + col] = o0;
        out[(q0+1)*DIN + col] = o1;
    }
}

extern "C" void kernel_launch(void* const* d_in, const int* in_sizes, int n_in,
                              void* d_out, int out_size, void* d_ws, size_t ws_size,
                              hipStream_t stream) {
    const float* x    = (const float*)d_in[0];
    const float* bias = (const float*)d_in[1];
    const float* lnw  = (const float*)d_in[2];
    const float* lnb  = (const float*)d_in[3];
    const float* lbw  = (const float*)d_in[4];
    const float* lbb  = (const float*)d_in[5];
    const float* Wq   = (const float*)d_in[6];
    const float* Wk   = (const float*)d_in[7];
    const float* Wv   = (const float*)d_in[8];
    const float* Wb   = (const float*)d_in[9];
    const float* Wg   = (const float*)d_in[10];
    const float* bg   = (const float*)d_in[11];
    const float* Wo   = (const float*)d_in[12];
    const float* bo   = (const float*)d_in[13];

    float* ws = (float*)d_ws;
    float* qb = ws + OFF_QB;
    float* kT = ws + OFF_KT;
    float* vb = ws + OFF_VB;
    float* gb = ws + OFF_GB;
    float* W2 = ws + OFF_W2;
    float* SC = ws + OFF_SC;
    float* lg = ws + OFF_LG;

    setup_kernel<<<1, 128, 0, stream>>>(lbw, lbb, Wb, W2, SC);
    proj_kernel<<<LQ/4, 256, 0, stream>>>(x, lnw, lnb, Wq, Wk, Wv, Wg, bg, qb, kT, vb, gb);
    bias_kernel<<<dim3(12, LQ), 256, 0, stream>>>(bias, W2, SC, lg);
    attn_kernel<<<LQ/2, 256, 0, stream>>>(lg, qb, kT, vb, gb, Wo, bo, (float*)d_out);
}

// Round 5
// 158.502 us; speedup vs baseline: 1.8208x; 1.3606x over previous
//
#include <hip/hip_runtime.h>

#define LQ 768
#define DIN 256
#define DB 128
#define NH 8
#define DH 32

// ws float offsets
#define OFF_QB 0
#define OFF_KT (LQ*DIN)          // kT[DIN][LQ]  (transposed, pre-scaled K)
#define OFF_VB (2*LQ*DIN)
#define OFF_GB (3*LQ*DIN)
#define OFF_W2 (4*LQ*DIN)
#define OFF_SC (OFF_W2 + DB*NH)
#define OFF_LG (OFF_SC + 16)

__device__ __forceinline__ void gload_lds16(const void* g, void* l) {
    __builtin_amdgcn_global_load_lds(
        (__attribute__((address_space(1))) const void*)g,
        (__attribute__((address_space(3))) void*)l,
        16, 0, 0);
}

// ---------------------------------------------------------------------------
// Setup: W2[d][h] = lbw[d]*Wb[d][h]; S[h] = sum_d W2; C[h] = sum_d lbb[d]*Wb.
// ---------------------------------------------------------------------------
__global__ __launch_bounds__(128) void setup_kernel(
    const float* __restrict__ lbw, const float* __restrict__ lbb,
    const float* __restrict__ Wb, float* __restrict__ W2, float* __restrict__ SC)
{
    const int d = threadIdx.x;          // 0..127
    const int lane = d & 63, wv = d >> 6;
    float w = lbw[d], b = lbb[d];
    float pS[NH], pC[NH];
    #pragma unroll
    for (int h = 0; h < NH; h++) {
        float wb = Wb[d*NH + h];
        float w2 = w * wb;
        W2[d*NH + h] = w2;
        pS[h] = w2;
        pC[h] = b * wb;
    }
    #pragma unroll
    for (int m = 1; m <= 32; m <<= 1) {
        #pragma unroll
        for (int h = 0; h < NH; h++) { pS[h] += __shfl_xor(pS[h], m); pC[h] += __shfl_xor(pC[h], m); }
    }
    __shared__ float red[2][16];
    if (lane == 0) {
        #pragma unroll
        for (int h = 0; h < NH; h++) { red[wv][h] = pS[h]; red[wv][NH+h] = pC[h]; }
    }
    __syncthreads();
    if (d < 16) SC[d] = red[0][d] + red[1][d];
}

// ---------------------------------------------------------------------------
// Proj: LN(x) + Q/K/V/gate. 4 rows/block. K written TRANSPOSED + pre-scaled.
// ---------------------------------------------------------------------------
__global__ __launch_bounds__(256) void proj_kernel(
    const float* __restrict__ x, const float* __restrict__ lnw, const float* __restrict__ lnb,
    const float* __restrict__ Wq, const float* __restrict__ Wk, const float* __restrict__ Wv,
    const float* __restrict__ Wg, const float* __restrict__ bg,
    float* __restrict__ qb, float* __restrict__ kT, float* __restrict__ vb, float* __restrict__ gb)
{
    const int tid = threadIdx.x;
    const int lane = tid & 63, rr = tid >> 6;
    const int row = blockIdx.x * 4 + rr;
    __shared__ float xn[4][DIN];

    float4 xv = ((const float4*)x)[row * (DIN/4) + lane];
    float s  = xv.x + xv.y + xv.z + xv.w;
    float ss = xv.x*xv.x + xv.y*xv.y + xv.z*xv.z + xv.w*xv.w;
    #pragma unroll
    for (int m = 1; m <= 32; m <<= 1) { s += __shfl_xor(s, m); ss += __shfl_xor(ss, m); }
    float mu  = s * (1.0f/DIN);
    float inv = rsqrtf(ss * (1.0f/DIN) - mu*mu + 1e-5f);
    float4 wv4 = ((const float4*)lnw)[lane];
    float4 bv4 = ((const float4*)lnb)[lane];
    float4 r4;
    r4.x = (xv.x - mu)*inv*wv4.x + bv4.x;
    r4.y = (xv.y - mu)*inv*wv4.y + bv4.y;
    r4.z = (xv.z - mu)*inv*wv4.z + bv4.z;
    r4.w = (xv.w - mu)*inv*wv4.w + bv4.w;
    *((float4*)&xn[rr][lane*4]) = r4;
    __syncthreads();

    const int col = tid;
    float aq[4] = {0,0,0,0}, ak[4] = {0,0,0,0}, av[4] = {0,0,0,0}, ag[4] = {0,0,0,0};
    for (int i4 = 0; i4 < DIN/4; i4++) {
        float4 x0 = *((const float4*)&xn[0][i4*4]);
        float4 x1 = *((const float4*)&xn[1][i4*4]);
        float4 x2 = *((const float4*)&xn[2][i4*4]);
        float4 x3 = *((const float4*)&xn[3][i4*4]);
        const float* p0 = (const float*)&x0;
        const float* p1 = (const float*)&x1;
        const float* p2 = (const float*)&x2;
        const float* p3 = (const float*)&x3;
        #pragma unroll
        for (int e = 0; e < 4; e++) {
            const int i = i4*4 + e;
            float wq = Wq[i*DIN + col], wk = Wk[i*DIN + col];
            float wvv = Wv[i*DIN + col], wg = Wg[i*DIN + col];
            aq[0] = fmaf(p0[e], wq, aq[0]); aq[1] = fmaf(p1[e], wq, aq[1]);
            aq[2] = fmaf(p2[e], wq, aq[2]); aq[3] = fmaf(p3[e], wq, aq[3]);
            ak[0] = fmaf(p0[e], wk, ak[0]); ak[1] = fmaf(p1[e], wk, ak[1]);
            ak[2] = fmaf(p2[e], wk, ak[2]); ak[3] = fmaf(p3[e], wk, ak[3]);
            av[0] = fmaf(p0[e], wvv, av[0]); av[1] = fmaf(p1[e], wvv, av[1]);
            av[2] = fmaf(p2[e], wvv, av[2]); av[3] = fmaf(p3[e], wvv, av[3]);
            ag[0] = fmaf(p0[e], wg, ag[0]); ag[1] = fmaf(p1[e], wg, ag[1]);
            ag[2] = fmaf(p2[e], wg, ag[2]); ag[3] = fmaf(p3[e], wg, ag[3]);
        }
    }
    const float kscale = 0.17677669529663687f;  // 1/sqrt(DH)
    float bgv = bg[col];
    #pragma unroll
    for (int r = 0; r < 4; r++) {
        const int orow = blockIdx.x*4 + r;
        qb[orow*DIN + col] = aq[r];
        vb[orow*DIN + col] = av[r];
        gb[orow*DIN + col] = 1.0f/(1.0f + __expf(-(ag[r] + bgv)));
    }
    *((float4*)&kT[col*LQ + blockIdx.x*4]) =
        make_float4(ak[0]*kscale, ak[1]*kscale, ak[2]*kscale, ak[3]*kscale);
}

// ---------------------------------------------------------------------------
// Bias stream (folded LN + @Wb -> logits). Grid (6, 768), block 128 (2 waves).
// Per wave: 64 keys as 4 x 16-key tiles, double-buffered 8KB LDS regions,
// staged via global_load_lds(16B) with pre-swizzled global source (LDS dest
// linear), counted vmcnt waits (8/10, never 0 in steady state). Lane =
// (q4=lane>>4 dim-quarter, key=lane&15); shuffle-reduce over q4; no barriers
// in the main loop. W2 in bank-staggered LDS (stride 264 -> disjoint banks).
// ---------------------------------------------------------------------------
__global__ __launch_bounds__(128) void bias_kernel(
    const float* __restrict__ bias, const float* __restrict__ W2g,
    const float* __restrict__ SCg, float* __restrict__ logits)
{
    __shared__ float tile[2][2][2048];   // [buf][wave][8KB]
    __shared__ float w2p[4*264];         // 4 q4-slabs, stride 264 (bank stagger 8)

    const int tid  = threadIdx.x;
    const int q    = blockIdx.y;
    const int w    = tid >> 6;
    const int lane = tid & 63;
    const int key  = lane & 15;
    const int q4   = lane >> 4;
    const int kwave = blockIdx.x * 128 + w * 64;

    for (int j = tid; j < 4*264; j += 128) {
        int g = j >> 8;  // not exact; recompute properly below
        g = j / 264;
        int rem = j - g*264;
        w2p[j] = (rem < 256) ? W2g[g*256 + rem] : 0.0f;
    }
    __syncthreads();   // w2p ready (drains everything once, before pipeline)

    float Sh[NH], Ch[NH];
    #pragma unroll
    for (int h = 0; h < NH; h++) { Sh[h] = SCg[h]; Ch[h] = SCg[NH + h]; }

    const char* gbase = (const char*)(bias + ((size_t)q*LQ + kwave)*DB);
    char* const lbase0 = (char*)&tile[0][w][0];
    char* const lbase1 = (char*)&tile[1][w][0];

    // stage tile t into buffer b: linear LDS dest, swizzled global src.
    // involution: sw(L) = L ^ (((L>>9)&15)<<4)  (XOR key-bits into bits 4..7)
    #define STAGE(t, lb)                                                     \
        {                                                                    \
            const char* gs = gbase + (size_t)(t)*8192;                       \
            _Pragma("unroll")                                                \
            for (int c = 0; c < 8; c++) {                                    \
                int L  = c*1024 + lane*16;                                   \
                int sw = L ^ (((L >> 9) & 15) << 4);                         \
                gload_lds16(gs + sw, (lb) + c*1024);                         \
            }                                                                \
        }

    STAGE(0, lbase0);
    asm volatile("" ::: "memory");      // keep stage0's 8 loads oldest
    STAGE(1, lbase1);

    const int rbase0 = ((key << 9) | (q4 << 7)) ^ (key << 4);

    #pragma unroll
    for (int t = 0; t < 4; t++) {
        if (t == 0)      asm volatile("s_waitcnt vmcnt(8)"  ::: "memory");
        else if (t < 3)  asm volatile("s_waitcnt vmcnt(10)" ::: "memory");
        else             asm volatile("s_waitcnt vmcnt(0)"  ::: "memory");

        const char* tw = (t & 1) ? lbase1 : lbase0;
        float s = 0.f, ss = 0.f;
        float acc[NH] = {0,0,0,0,0,0,0,0};
        #pragma unroll
        for (int j = 0; j < 8; j++) {
            float4 v = *(const float4*)(tw + (rbase0 ^ (j << 4)));
            const float* wp = &w2p[q4*264 + j*32];
            #pragma unroll
            for (int e = 0; e < 4; e++) {
                float xv = (&v.x)[e];
                s += xv; ss = fmaf(xv, xv, ss);
                float4 w0 = *(const float4*)(wp + e*8);
                float4 w1 = *(const float4*)(wp + e*8 + 4);
                acc[0] = fmaf(xv, w0.x, acc[0]); acc[1] = fmaf(xv, w0.y, acc[1]);
                acc[2] = fmaf(xv, w0.z, acc[2]); acc[3] = fmaf(xv, w0.w, acc[3]);
                acc[4] = fmaf(xv, w1.x, acc[4]); acc[5] = fmaf(xv, w1.y, acc[5]);
                acc[6] = fmaf(xv, w1.z, acc[6]); acc[7] = fmaf(xv, w1.w, acc[7]);
            }
        }
        #pragma unroll
        for (int m = 16; m <= 32; m <<= 1) {
            s += __shfl_xor(s, m); ss += __shfl_xor(ss, m);
            #pragma unroll
            for (int h = 0; h < NH; h++) acc[h] += __shfl_xor(acc[h], m);
        }
        if (q4 == 0) {
            float mu  = s * (1.0f/DB);
            float inv = rsqrtf(ss * (1.0f/DB) - mu*mu + 1e-5f);
            float lo[NH];
            #pragma unroll
            for (int h = 0; h < NH; h++)
                lo[h] = fmaf(inv, acc[h] - mu*Sh[h], Ch[h]);
            float4* dst = (float4*)(logits + ((size_t)q*LQ + kwave + t*16 + key)*NH);
            dst[0] = make_float4(lo[0], lo[1], lo[2], lo[3]);
            dst[1] = make_float4(lo[4], lo[5], lo[6], lo[7]);
        }
        asm volatile("" ::: "memory");  // ds_reads of this buffer issue before restage
        if (t + 2 < 4) {
            char* nb = (t & 1) ? lbase1 : lbase0;
            STAGE(t + 2, nb);
        }
    }
    #undef STAGE
}

// ---------------------------------------------------------------------------
// Attn: logits -> pT[r][h][k] (transposed, padded 776), add qk from kT,
// softmax along contiguous rows (float4), PV with broadcast float4 p-reads,
// gate, Wo. 2 q-rows per block, grid 384.
// ---------------------------------------------------------------------------
__global__ __launch_bounds__(256) void attn_kernel(
    const float* __restrict__ logits, const float* __restrict__ qbuf,
    const float* __restrict__ kT, const float* __restrict__ vbuf,
    const float* __restrict__ gb, const float* __restrict__ Wo,
    const float* __restrict__ bo, float* __restrict__ out)
{
    const int tid = threadIdx.x;
    const int q0 = blockIdx.x * 2;
    __shared__ float pT[2][NH][776];
    __shared__ float ao[2][DIN];
    __shared__ float isum[2][NH];

    #pragma unroll
    for (int r = 0; r < 2; r++) {
        const float4* rp = (const float4*)(logits + (size_t)(q0 + r)*LQ*NH);
        #pragma unroll
        for (int ii = 0; ii < 6; ii++) {
            int jj = ii*256 + tid;
            float4 t = rp[jj];
            int k = jj >> 1, h0 = (jj & 1) << 2;
            pT[r][h0+0][k] = t.x; pT[r][h0+1][k] = t.y;
            pT[r][h0+2][k] = t.z; pT[r][h0+3][k] = t.w;
        }
    }
    __syncthreads();

    if (tid < 192) {
        const float* q0p = qbuf + (size_t)q0*DIN;
        const float* q1p = q0p + DIN;
        #pragma unroll
        for (int h = 0; h < NH; h++) {
            float a00=0,a01=0,a02=0,a03=0, a10=0,a11=0,a12=0,a13=0;
            #pragma unroll
            for (int dd = 0; dd < DH; dd++) {
                const int d = h*DH + dd;
                float4 kv = *(const float4*)(kT + (size_t)d*LQ + tid*4);
                float qa = q0p[d], qc = q1p[d];
                a00 = fmaf(qa, kv.x, a00); a01 = fmaf(qa, kv.y, a01);
                a02 = fmaf(qa, kv.z, a02); a03 = fmaf(qa, kv.w, a03);
                a10 = fmaf(qc, kv.x, a10); a11 = fmaf(qc, kv.y, a11);
                a12 = fmaf(qc, kv.z, a12); a13 = fmaf(qc, kv.w, a13);
            }
            float4 p0 = *(float4*)&pT[0][h][tid*4];
            p0.x += a00; p0.y += a01; p0.z += a02; p0.w += a03;
            *(float4*)&pT[0][h][tid*4] = p0;
            float4 p1 = *(float4*)&pT[1][h][tid*4];
            p1.x += a10; p1.y += a11; p1.z += a12; p1.w += a13;
            *(float4*)&pT[1][h][tid*4] = p1;
        }
    }
    __syncthreads();

    {
        const int r = tid >> 7, h = (tid >> 4) & 7, l = tid & 15;
        float4* row = (float4*)&pT[r][h][0];
        float m = -1e30f;
        for (int i = l; i < 192; i += 16) {
            float4 v = row[i];
            m = fmaxf(m, fmaxf(fmaxf(v.x, v.y), fmaxf(v.z, v.w)));
        }
        #pragma unroll
        for (int mm = 1; mm <= 8; mm <<= 1) m = fmaxf(m, __shfl_xor(m, mm));
        float sum = 0.f;
        for (int i = l; i < 192; i += 16) {
            float4 v = row[i];
            v.x = __expf(v.x - m); v.y = __expf(v.y - m);
            v.z = __expf(v.z - m); v.w = __expf(v.w - m);
            sum += v.x + v.y + v.z + v.w;
            row[i] = v;
        }
        #pragma unroll
        for (int mm = 1; mm <= 8; mm <<= 1) sum += __shfl_xor(sum, mm);
        if (l == 0) isum[r][h] = 1.0f / sum;
    }
    __syncthreads();

    {
        const int h = tid >> 5, d = tid & 31;
        const float* vp = vbuf + h*DH + d;
        const float4* p0r = (const float4*)&pT[0][h][0];
        const float4* p1r = (const float4*)&pT[1][h][0];
        float a0 = 0.f, a1 = 0.f;
        for (int k4 = 0; k4 < 192; k4++) {
            float4 p0 = p0r[k4], p1 = p1r[k4];
            float v0 = vp[(size_t)(k4*4+0)*DIN];
            float v1 = vp[(size_t)(k4*4+1)*DIN];
            float v2 = vp[(size_t)(k4*4+2)*DIN];
            float v3 = vp[(size_t)(k4*4+3)*DIN];
            a0 = fmaf(p0.x, v0, a0); a0 = fmaf(p0.y, v1, a0);
            a0 = fmaf(p0.z, v2, a0); a0 = fmaf(p0.w, v3, a0);
            a1 = fmaf(p1.x, v0, a1); a1 = fmaf(p1.y, v1, a1);
            a1 = fmaf(p1.z, v2, a1); a1 = fmaf(p1.w, v3, a1);
        }
        ao[0][tid] = a0 * isum[0][h] * gb[(q0+0)*DIN + tid];
        ao[1][tid] = a1 * isum[1][h] * gb[(q0+1)*DIN + tid];
    }
    __syncthreads();

    {
        const int col = tid;
        float o0 = bo[col], o1 = o0;
        for (int i = 0; i < DIN; i++) {
            float wv = Wo[i*DIN + col];
            o0 = fmaf(ao[0][i], wv, o0);
            o1 = fmaf(ao[1][i], wv, o1);
        }
        out[(q0+0)*DIN + col] = o0;
        out[(q0+1)*DIN + col] = o1;
    }
}

extern "C" void kernel_launch(void* const* d_in, const int* in_sizes, int n_in,
                              void* d_out, int out_size, void* d_ws, size_t ws_size,
                              hipStream_t stream) {
    const float* x    = (const float*)d_in[0];
    const float* bias = (const float*)d_in[1];
    const float* lnw  = (const float*)d_in[2];
    const float* lnb  = (const float*)d_in[3];
    const float* lbw  = (const float*)d_in[4];
    const float* lbb  = (const float*)d_in[5];
    const float* Wq   = (const float*)d_in[6];
    const float* Wk   = (const float*)d_in[7];
    const float* Wv   = (const float*)d_in[8];
    const float* Wb   = (const float*)d_in[9];
    const float* Wg   = (const float*)d_in[10];
    const float* bg   = (const float*)d_in[11];
    const float* Wo   = (const float*)d_in[12];
    const float* bo   = (const float*)d_in[13];

    float* ws = (float*)d_ws;
    float* qb = ws + OFF_QB;
    float* kT = ws + OFF_KT;
    float* vb = ws + OFF_VB;
    float* gb = ws + OFF_GB;
    float* W2 = ws + OFF_W2;
    float* SC = ws + OFF_SC;
    float* lg = ws + OFF_LG;

    setup_kernel<<<1, 128, 0, stream>>>(lbw, lbb, Wb, W2, SC);
    proj_kernel<<<LQ/4, 256, 0, stream>>>(x, lnw, lnb, Wq, Wk, Wv, Wg, bg, qb, kT, vb, gb);
    bias_kernel<<<dim3(6, LQ), 128, 0, stream>>>(bias, W2, SC, lg);
    attn_kernel<<<LQ/2, 256, 0, stream>>>(lg, qb, kT, vb, gb, Wo, bo, (float*)d_out);
}